// Round 10
// baseline (730.015 us; speedup 1.0000x reference)
//
#include <hip/hip_runtime.h>
#include <hip/hip_fp16.h>
#include <math.h>

#define BD 256
#define CAP 192
#define PBLK 2048

#define RED16(v) { v += __shfl_xor(v, 1, 64); v += __shfl_xor(v, 2, 64); \
                   v += __shfl_xor(v, 4, 64); v += __shfl_xor(v, 8, 64); }
#define REDQ(v)  { v += __shfl_xor(v, 16, 64); v += __shfl_xor(v, 32, 64); }

// ---------------- init: res = emb_cur = entity_emb; deg = 0 ----------------
__global__ void k_init(const float4* __restrict__ ent, float4* __restrict__ emb,
                       float4* __restrict__ out, int n4, int* __restrict__ deg, int N) {
  int i = blockIdx.x * BD + threadIdx.x;
  if (i < n4) { float4 v = ent[i]; emb[i] = v; out[i] = v; }
  if (i < N) deg[i] = 0;
}

// ---------------- CSR build ----------------
__global__ void k_deg(const int* __restrict__ head, int* __restrict__ deg, int E) {
  int e = blockIdx.x * BD + threadIdx.x;
  if (e < E) atomicAdd(&deg[head[e]], 1);
}

__global__ void k_scan_a(const int* __restrict__ deg, int* __restrict__ rowptr,
                         int* __restrict__ bsum, int N) {
  __shared__ int s[BD];
  int t = threadIdx.x, i = blockIdx.x * BD + t;
  int v = (i < N) ? deg[i] : 0;
  s[t] = v; __syncthreads();
  for (int off = 1; off < BD; off <<= 1) {
    int add = (t >= off) ? s[t - off] : 0;
    __syncthreads();
    s[t] += add;
    __syncthreads();
  }
  if (i < N) rowptr[i] = s[t] - v;
  if (t == BD - 1) bsum[blockIdx.x] = s[t];
}

__global__ void k_scan_b(const int* __restrict__ bsum, int* __restrict__ boff, int nb) {
  __shared__ int s[512];
  int t = threadIdx.x;
  int v = (t < nb) ? bsum[t] : 0;
  s[t] = v; __syncthreads();
  for (int off = 1; off < 512; off <<= 1) {
    int add = (t >= off) ? s[t - off] : 0;
    __syncthreads();
    s[t] += add;
    __syncthreads();
  }
  boff[t] = s[t] - v;
}

__global__ void k_scan_c(int* __restrict__ rowptr, int* __restrict__ cur,
                         const int* __restrict__ boff, int N, int E) {
  int i = blockIdx.x * BD + threadIdx.x;
  if (i < N) { int v = rowptr[i] + boff[blockIdx.x]; rowptr[i] = v; cur[i] = v; }
  if (i == 0) rowptr[N] = E;
}

__global__ void k_scatter(const int* __restrict__ head, const int* __restrict__ tail,
                          const int* __restrict__ etype,
                          int* __restrict__ cur, int2* __restrict__ epack, int E) {
  int e = blockIdx.x * BD + threadIdx.x;
  if (e < E) {
    int p = atomicAdd(&cur[head[e]], 1);
    epack[p] = make_int2(tail[e], etype[e] - 1);
  }
}

// ---------------- M_h = Wq_h @ Wk_h^T : Mf[m][i*4+h] ----------------
__global__ void k_m(const float* __restrict__ Wq, const float* __restrict__ Wk,
                    float* __restrict__ Mf) {
  int tid = blockIdx.x * BD + threadIdx.x;   // 0..16383
  int c = tid & 255;
  int m = tid >> 8;
  int i = c >> 2, h = c & 3;
  const float* wq = Wq + m * 64 + h * 16;
  const float* wk = Wk + i * 64 + h * 16;
  float acc = 0.f;
#pragma unroll
  for (int d = 0; d < 16; d++) acc = fmaf(wq[d], wk[d], acc);
  Mf[tid] = acc;
}

// ---------------- G = emb @ Mf  -> fp16  (LDS-tiled, 64 nodes/block) ----------------
__global__ __launch_bounds__(256) void k_g(const float* __restrict__ emb,
                                           const float* __restrict__ Mf,
                                           uint2* __restrict__ Gh2, int N) {
  __shared__ float lM[64 * 256];             // 64 KB
  int t = threadIdx.x;
  const float4* Mf4 = (const float4*)Mf;
  float4* lM4 = (float4*)lM;
  for (int i = t; i < 4096; i += BD) lM4[i] = Mf4[i];
  __syncthreads();
  int lane = t & 63, w = t >> 6;
  int nloc0 = blockIdx.x * 64 + w * 16;
#pragma unroll
  for (int b = 0; b < 2; b++) {
    int nl = nloc0 + b * 8;
    float4 acc[8];
#pragma unroll
    for (int ni = 0; ni < 8; ni++) acc[ni] = make_float4(0.f, 0.f, 0.f, 0.f);
#pragma unroll 8
    for (int m = 0; m < 64; m++) {
      float4 Mv = lM4[m * 64 + lane];
#pragma unroll
      for (int ni = 0; ni < 8; ni++) {
        float em = emb[(size_t)(nl + ni) * 64 + m];   // over-read past N stays in ws
        acc[ni].x = fmaf(em, Mv.x, acc[ni].x);
        acc[ni].y = fmaf(em, Mv.y, acc[ni].y);
        acc[ni].z = fmaf(em, Mv.z, acc[ni].z);
        acc[ni].w = fmaf(em, Mv.w, acc[ni].w);
      }
    }
#pragma unroll
    for (int ni = 0; ni < 8; ni++)
      if (nl + ni < N) {
        __half2 h01 = __floats2half2_rn(acc[ni].x, acc[ni].y);
        __half2 h23 = __floats2half2_rn(acc[ni].z, acc[ni].w);
        uint2 st;
        st.x = *(unsigned int*)&h01;
        st.y = *(unsigned int*)&h23;
        Gh2[(size_t)(nl + ni) * 64 + lane] = st;
      }
  }
}

// ---------------- fused: att + softmax-den + S + S@Wv -> kg  (persistent, G in LDS) ----------------
__global__ __launch_bounds__(256) void k_fused(const float* __restrict__ emb,
                        const float* __restrict__ weight,
                        const uint4* __restrict__ Ghq, const float* __restrict__ Wv,
                        const int2* __restrict__ epack, const int* __restrict__ rowptr,
                        float* __restrict__ kg, int N) {
  __shared__ float GLs[4][16][20];           // per-wave G rows, 80B stride (16B-aligned)
  __shared__ float SL[4 * 272];              // per-wave 4 segments of 68 (bank-skewed)
  int t = threadIdx.x, lane = t & 63, w = t >> 6, q = lane >> 4, s = lane & 15;
  float* L = SL + w * 272;
  float* Grow = &GLs[w][s][0];
  int wid = blockIdx.x * 4 + w, nw = gridDim.x * 4;
  for (int n = wid; n < N; n += nw) {
    // stage this node's G row (fp16 -> f32) into wave-local LDS; quarter 0 only
    if (q == 0) {
      uint4 ga = Ghq[(size_t)n * 32 + s * 2];
      uint4 gb = Ghq[(size_t)n * 32 + s * 2 + 1];
      float2 c0 = __half22float2(*(__half2*)&ga.x);
      float2 c1 = __half22float2(*(__half2*)&ga.y);
      *(float4*)(Grow)      = make_float4(c0.x, c0.y, c1.x, c1.y);
      c0 = __half22float2(*(__half2*)&ga.z);
      c1 = __half22float2(*(__half2*)&ga.w);
      *(float4*)(Grow + 4)  = make_float4(c0.x, c0.y, c1.x, c1.y);
      c0 = __half22float2(*(__half2*)&gb.x);
      c1 = __half22float2(*(__half2*)&gb.y);
      *(float4*)(Grow + 8)  = make_float4(c0.x, c0.y, c1.x, c1.y);
      c0 = __half22float2(*(__half2*)&gb.z);
      c1 = __half22float2(*(__half2*)&gb.w);
      *(float4*)(Grow + 12) = make_float4(c0.x, c0.y, c1.x, c1.y);
    }
    // wave-synchronous: ds_write by q==0 ordered before ds_read below via waitcnt

    int base = rowptr[n], deg = rowptr[n + 1] - base;
    float4 den = make_float4(0.f, 0.f, 0.f, 0.f);
    float4 S0 = den, S1 = den, S2 = den, S3 = den;
    for (int g0 = 0; g0 < deg; g0 += 4) {
      // re-read G each group; offset is 0 at runtime (g0 < 2^20) but opaque -> no LICM
      const float4* Gv = (const float4*)(Grow + ((unsigned)(g0 >> 20) & ~3u));
      float4 G0 = Gv[0], G1 = Gv[1], G2 = Gv[2], G3 = Gv[3];
      int k = g0 + q;
      bool valid = (k < deg);
      int kk = min(k, deg - 1);
      int2 p = epack[base + kk];
      float4 e4 = *(const float4*)(emb + (size_t)p.x * 64 + s * 4);
      float4 r4 = *(const float4*)(weight + (size_t)p.y * 64 + s * 4);
      float4 x;
      x.x = e4.x * r4.x; x.y = e4.y * r4.y; x.z = e4.z * r4.z; x.w = e4.w * r4.w;
      float4 a;
      a.x = fmaf(x.x, G0.x, fmaf(x.y, G1.x, fmaf(x.z, G2.x, x.w * G3.x)));
      a.y = fmaf(x.x, G0.y, fmaf(x.y, G1.y, fmaf(x.z, G2.y, x.w * G3.y)));
      a.z = fmaf(x.x, G0.z, fmaf(x.y, G1.z, fmaf(x.z, G2.z, x.w * G3.z)));
      a.w = fmaf(x.x, G0.w, fmaf(x.y, G1.w, fmaf(x.z, G2.w, x.w * G3.w)));
      RED16(a.x) RED16(a.y) RED16(a.z) RED16(a.w)
      a.x = fminf(10.f, fmaxf(-10.f, a.x));
      a.y = fminf(10.f, fmaxf(-10.f, a.y));
      a.z = fminf(10.f, fmaxf(-10.f, a.z));
      a.w = fminf(10.f, fmaxf(-10.f, a.w));
      float4 ev;
      ev.x = valid ? __expf(a.x) : 0.f;
      ev.y = valid ? __expf(a.y) : 0.f;
      ev.z = valid ? __expf(a.z) : 0.f;
      ev.w = valid ? __expf(a.w) : 0.f;
      den.x += ev.x; den.y += ev.y; den.z += ev.z; den.w += ev.w;
      S0.x = fmaf(ev.x, x.x, S0.x); S0.y = fmaf(ev.y, x.x, S0.y);
      S0.z = fmaf(ev.z, x.x, S0.z); S0.w = fmaf(ev.w, x.x, S0.w);
      S1.x = fmaf(ev.x, x.y, S1.x); S1.y = fmaf(ev.y, x.y, S1.y);
      S1.z = fmaf(ev.z, x.y, S1.z); S1.w = fmaf(ev.w, x.y, S1.w);
      S2.x = fmaf(ev.x, x.z, S2.x); S2.y = fmaf(ev.y, x.z, S2.y);
      S2.z = fmaf(ev.z, x.z, S2.z); S2.w = fmaf(ev.w, x.z, S2.w);
      S3.x = fmaf(ev.x, x.w, S3.x); S3.y = fmaf(ev.y, x.w, S3.y);
      S3.z = fmaf(ev.z, x.w, S3.z); S3.w = fmaf(ev.w, x.w, S3.w);
    }
    REDQ(den.x) REDQ(den.y) REDQ(den.z) REDQ(den.w)
    REDQ(S0.x) REDQ(S0.y) REDQ(S0.z) REDQ(S0.w)
    REDQ(S1.x) REDQ(S1.y) REDQ(S1.z) REDQ(S1.w)
    REDQ(S2.x) REDQ(S2.y) REDQ(S2.z) REDQ(S2.w)
    REDQ(S3.x) REDQ(S3.y) REDQ(S3.z) REDQ(S3.w)
    float4 inv;
    inv.x = 1.f / (den.x + 1e-8f); inv.y = 1.f / (den.y + 1e-8f);
    inv.z = 1.f / (den.z + 1e-8f); inv.w = 1.f / (den.w + 1e-8f);
    S0.x *= inv.x; S0.y *= inv.y; S0.z *= inv.z; S0.w *= inv.w;
    S1.x *= inv.x; S1.y *= inv.y; S1.z *= inv.z; S1.w *= inv.w;
    S2.x *= inv.x; S2.y *= inv.y; S2.z *= inv.z; S2.w *= inv.w;
    S3.x *= inv.x; S3.y *= inv.y; S3.z *= inv.z; S3.w *= inv.w;
    if (q == 0) {
      *(float4*)(L +       s * 4) = make_float4(S0.x, S1.x, S2.x, S3.x);
      *(float4*)(L +  68 + s * 4) = make_float4(S0.y, S1.y, S2.y, S3.y);
      *(float4*)(L + 136 + s * 4) = make_float4(S0.z, S1.z, S2.z, S3.z);
      *(float4*)(L + 204 + s * 4) = make_float4(S0.w, S1.w, S2.w, S3.w);
    }
    const float4* L4 = (const float4*)(L + q * 68);
    float acc = 0.f;
#pragma unroll
    for (int i4 = 0; i4 < 16; i4++) {
      float4 Lv = L4[i4];
      acc = fmaf(Lv.x, Wv[(i4 * 4 + 0) * 64 + lane], acc);
      acc = fmaf(Lv.y, Wv[(i4 * 4 + 1) * 64 + lane], acc);
      acc = fmaf(Lv.z, Wv[(i4 * 4 + 2) * 64 + lane], acc);
      acc = fmaf(Lv.w, Wv[(i4 * 4 + 3) * 64 + lane], acc);
    }
    kg[(size_t)n * 64 + lane] = acc;
  }
}

// ---------------- D = KG^2 @ REL^2T  (64 nodes/block, LDS-staged) ----------------
__global__ __launch_bounds__(256) void k_d(const float4* __restrict__ kg4,
                    const float* __restrict__ weight,
                    float* __restrict__ D, int N) {
  __shared__ float R2T[64 * 32];       // [j][r] = weight[r][j]^2
  __shared__ float KG2[64 * 68];       // [node][j] padded
  int t = threadIdx.x;
  for (int i = t; i < 2048; i += BD) {
    int j = i >> 5, r = i & 31;
    float v = (r < 31) ? weight[r * 64 + j] : 0.f;
    R2T[i] = v * v;
  }
  int nbase = blockIdx.x * 64;
  const float4* src = kg4 + (size_t)nbase * 16;
#pragma unroll
  for (int i = 0; i < 4; i++) {
    int idx = t + i * 256;
    float4 v = src[idx];               // may over-read past N into adjacent ws: safe
    float* dst = KG2 + (idx >> 4) * 68 + (idx & 15) * 4;
    dst[0] = v.x * v.x; dst[1] = v.y * v.y; dst[2] = v.z * v.z; dst[3] = v.w * v.w;
  }
  __syncthreads();
  int r = t & 31, ng = t >> 5;
  float acc[8] = {0.f, 0.f, 0.f, 0.f, 0.f, 0.f, 0.f, 0.f};
  const float* kbase = KG2 + ng * 8 * 68;
#pragma unroll 4
  for (int j4 = 0; j4 < 16; j4++) {
    float r0 = R2T[(j4 * 4 + 0) * 32 + r];
    float r1 = R2T[(j4 * 4 + 1) * 32 + r];
    float r2 = R2T[(j4 * 4 + 2) * 32 + r];
    float r3 = R2T[(j4 * 4 + 3) * 32 + r];
#pragma unroll
    for (int ni = 0; ni < 8; ni++) {
      float4 kv = *(const float4*)(kbase + ni * 68 + j4 * 4);
      acc[ni] = fmaf(kv.w, r3, fmaf(kv.z, r2, fmaf(kv.y, r1, fmaf(kv.x, r0, acc[ni]))));
    }
  }
  if (r < 31) {
    int nlim = N - nbase;
#pragma unroll
    for (int ni = 0; ni < 8; ni++) {
      int nl = ng * 8 + ni;
      if (nl < nlim) D[(size_t)(nbase + nl) * 32 + r] = acc[ni];
    }
  }
}

// ---------------- scatter-softmax + aggregation + normalize + residual (persistent) ----------------
__global__ __launch_bounds__(256) void k_aggnorm(const float* __restrict__ emb,
                          const float* __restrict__ D,
                          const int2* __restrict__ epack, const int* __restrict__ rowptr,
                          float* __restrict__ embn, float* __restrict__ out, int N) {
  __shared__ float wls[4 * CAP];
  __shared__ float DnL[4 * 32];
  int t = threadIdx.x, lane = t & 63, w = t >> 6, q = lane >> 4, s = lane & 15;
  float* wl = wls + w * CAP;
  float* Dn = DnL + w * 32;
  int wid = blockIdx.x * 4 + w, nw = gridDim.x * 4;
  for (int n = wid; n < N; n += nw) {
    int base = rowptr[n], deg = rowptr[n + 1] - base;
    if (lane < 32) Dn[lane] = (lane < 31) ? D[(size_t)n * 32 + lane] : 0.f;
    float4 agg = make_float4(0.f, 0.f, 0.f, 0.f);
    float sacc = 0.f;
    float m = -1e30f;
    if (deg > 0) {
      for (int k = lane; k < deg; k += 64) {
        int2 p = epack[base + k];
        float wv = Dn[p.y] * D[(size_t)p.x * 32 + p.y];
        if (k < CAP) wl[k] = wv;
        m = fmaxf(m, wv);
      }
#pragma unroll
      for (int off = 32; off >= 1; off >>= 1) m = fmaxf(m, __shfl_xor(m, off, 64));
      for (int g0 = 0; g0 < deg; g0 += 4) {
        int k = g0 + q;
        bool valid = (k < deg);
        int kk = min(k, deg - 1);
        int2 p = epack[base + kk];
        float4 e4 = *(const float4*)(emb + (size_t)p.x * 64 + s * 4);
        float wv = (kk < CAP) ? wl[kk] : Dn[p.y] * D[(size_t)p.x * 32 + p.y];
        float a = valid ? __expf(wv - m) : 0.f;
        sacc += a;
        agg.x = fmaf(a, e4.x, agg.x);
        agg.y = fmaf(a, e4.y, agg.y);
        agg.z = fmaf(a, e4.z, agg.z);
        agg.w = fmaf(a, e4.w, agg.w);
      }
    }
    REDQ(sacc)
    REDQ(agg.x) REDQ(agg.y) REDQ(agg.z) REDQ(agg.w)
    float sinv = 1.f / (sacc + 1e-16f);
    agg.x *= sinv; agg.y *= sinv; agg.z *= sinv; agg.w *= sinv;
    float ss = agg.x * agg.x + agg.y * agg.y + agg.z * agg.z + agg.w * agg.w;
    RED16(ss)
    float nr = fmaxf(sqrtf(ss), 1e-12f);
    float rin = 1.f / nr;
    float4 en;
    en.x = agg.x * rin; en.y = agg.y * rin; en.z = agg.z * rin; en.w = agg.w * rin;
    if (q == 0) {
      float4* eo = (float4*)(embn + (size_t)n * 64) + s;
      *eo = en;
      float4* oo = (float4*)(out + (size_t)n * 64) + s;
      float4 ov = *oo;
      ov.x += en.x; ov.y += en.y; ov.z += en.z; ov.w += en.w;
      *oo = ov;
    }
  }
}

extern "C" void kernel_launch(void* const* d_in, const int* in_sizes, int n_in,
                              void* d_out, int out_size, void* d_ws, size_t ws_size,
                              hipStream_t stream) {
  const float* ent    = (const float*)d_in[0];
  const float* weight = (const float*)d_in[1];
  const float* Wq     = (const float*)d_in[2];
  const float* Wk     = (const float*)d_in[3];
  const float* Wv     = (const float*)d_in[4];
  const int*   eidx   = (const int*)d_in[5];
  const int*   etype  = (const int*)d_in[6];
  int N = in_sizes[0] / 64;
  int E = in_sizes[6];
  const int* head = eidx;
  const int* tail = eidx + E;

  // workspace layout (float units)
  float* ws   = (float*)d_ws;
  size_t o = 0;
  float* embA = ws + o; o += (size_t)N * 64;
  float* embB = ws + o; o += (size_t)N * 64;
  float* Gbuf = ws + o; o += (size_t)N * 128;    // fp16 G (N*256 halves); reused as D (N*32 f32)
  float* Mf   = ws + o; o += 64 * 256;
  int2* epack = (int2*)(ws + o); o += (size_t)E * 2;
  int* rowptr = (int*)(ws + o); o += N + 1;
  int* deg    = (int*)(ws + o); o += N;
  int* cur    = (int*)(ws + o); o += N;
  int* bsum   = (int*)(ws + o); o += 512;
  int* boff   = (int*)(ws + o); o += 512;
  float* Dbuf = Gbuf;

  int n4  = N * 64 / 4;
  int bl4 = (n4 + BD - 1) / BD;
  int ebl = (E + BD - 1) / BD;
  int sbl = (N + BD - 1) / BD;

  k_init<<<bl4, BD, 0, stream>>>((const float4*)ent, (float4*)embA, (float4*)d_out,
                                 n4, deg, N);
  k_deg    <<<ebl, BD, 0, stream>>>(head, deg, E);
  k_scan_a <<<sbl, BD, 0, stream>>>(deg, rowptr, bsum, N);
  k_scan_b <<<1, 512, 0, stream>>>(bsum, boff, sbl);
  k_scan_c <<<sbl, BD, 0, stream>>>(rowptr, cur, boff, N, E);
  k_scatter<<<ebl, BD, 0, stream>>>(head, tail, etype, cur, epack, E);

  float* emb = embA;
  float* alt = embB;
  for (int l = 0; l < 2; l++) {
    const float* wq = Wq + (size_t)l * 64 * 64;
    const float* wk = Wk + (size_t)l * 64 * 64;
    const float* wv = Wv + (size_t)l * 64 * 64;

    k_m<<<64, BD, 0, stream>>>(wq, wk, Mf);
    k_g<<<(N + 63) / 64, BD, 0, stream>>>(emb, Mf, (uint2*)Gbuf, N);
    k_fused<<<PBLK, BD, 0, stream>>>(emb, weight, (const uint4*)Gbuf,
                                     wv, epack, rowptr, alt, N);
    k_d<<<(N + 63) / 64, BD, 0, stream>>>((const float4*)alt, weight, Dbuf, N);
    k_aggnorm<<<PBLK, BD, 0, stream>>>(emb, Dbuf, epack, rowptr,
                                       alt, (float*)d_out, N);
    float* tmp = emb; emb = alt; alt = tmp;
  }
}

// Round 11
// 640.090 us; speedup vs baseline: 1.1405x; 1.1405x over previous
//
#include <hip/hip_runtime.h>
#include <hip/hip_fp16.h>
#include <math.h>

#define BD 256
#define CAP 192
#define PBLK 2048

#define RED16(v) { v += __shfl_xor(v, 1, 64); v += __shfl_xor(v, 2, 64); \
                   v += __shfl_xor(v, 4, 64); v += __shfl_xor(v, 8, 64); }
#define REDQ(v)  { v += __shfl_xor(v, 16, 64); v += __shfl_xor(v, 32, 64); }

__device__ __forceinline__ __half2 shflxor_h2(__half2 v, int off) {
  int i = __shfl_xor(*(int*)&v, off, 64);
  return *(__half2*)&i;
}
#define REDQH(v) { v = __hadd2(v, shflxor_h2(v, 16)); v = __hadd2(v, shflxor_h2(v, 32)); }

// ---------------- init: res = emb_cur = entity_emb; deg = 0 ----------------
__global__ void k_init(const float4* __restrict__ ent, float4* __restrict__ emb,
                       float4* __restrict__ out, int n4, int* __restrict__ deg, int N) {
  int i = blockIdx.x * BD + threadIdx.x;
  if (i < n4) { float4 v = ent[i]; emb[i] = v; out[i] = v; }
  if (i < N) deg[i] = 0;
}

// ---------------- CSR build ----------------
__global__ void k_deg(const int* __restrict__ head, int* __restrict__ deg, int E) {
  int e = blockIdx.x * BD + threadIdx.x;
  if (e < E) atomicAdd(&deg[head[e]], 1);
}

__global__ void k_scan_a(const int* __restrict__ deg, int* __restrict__ rowptr,
                         int* __restrict__ bsum, int N) {
  __shared__ int s[BD];
  int t = threadIdx.x, i = blockIdx.x * BD + t;
  int v = (i < N) ? deg[i] : 0;
  s[t] = v; __syncthreads();
  for (int off = 1; off < BD; off <<= 1) {
    int add = (t >= off) ? s[t - off] : 0;
    __syncthreads();
    s[t] += add;
    __syncthreads();
  }
  if (i < N) rowptr[i] = s[t] - v;
  if (t == BD - 1) bsum[blockIdx.x] = s[t];
}

__global__ void k_scan_b(const int* __restrict__ bsum, int* __restrict__ boff, int nb) {
  __shared__ int s[512];
  int t = threadIdx.x;
  int v = (t < nb) ? bsum[t] : 0;
  s[t] = v; __syncthreads();
  for (int off = 1; off < 512; off <<= 1) {
    int add = (t >= off) ? s[t - off] : 0;
    __syncthreads();
    s[t] += add;
    __syncthreads();
  }
  boff[t] = s[t] - v;
}

__global__ void k_scan_c(int* __restrict__ rowptr, int* __restrict__ cur,
                         const int* __restrict__ boff, int N, int E) {
  int i = blockIdx.x * BD + threadIdx.x;
  if (i < N) { int v = rowptr[i] + boff[blockIdx.x]; rowptr[i] = v; cur[i] = v; }
  if (i == 0) rowptr[N] = E;
}

__global__ void k_scatter(const int* __restrict__ head, const int* __restrict__ tail,
                          const int* __restrict__ etype,
                          int* __restrict__ cur, int2* __restrict__ epack, int E) {
  int e = blockIdx.x * BD + threadIdx.x;
  if (e < E) {
    int p = atomicAdd(&cur[head[e]], 1);
    epack[p] = make_int2(tail[e], etype[e] - 1);
  }
}

// ---------------- M_h = Wq_h @ Wk_h^T : Mf[m][i*4+h] ----------------
__global__ void k_m(const float* __restrict__ Wq, const float* __restrict__ Wk,
                    float* __restrict__ Mf) {
  int tid = blockIdx.x * BD + threadIdx.x;   // 0..16383
  int c = tid & 255;
  int m = tid >> 8;
  int i = c >> 2, h = c & 3;
  const float* wq = Wq + m * 64 + h * 16;
  const float* wk = Wk + i * 64 + h * 16;
  float acc = 0.f;
#pragma unroll
  for (int d = 0; d < 16; d++) acc = fmaf(wq[d], wk[d], acc);
  Mf[tid] = acc;
}

// ---------------- G = emb @ Mf  -> fp16  (LDS-tiled, 64 nodes/block) ----------------
__global__ __launch_bounds__(256) void k_g(const float* __restrict__ emb,
                                           const float* __restrict__ Mf,
                                           uint2* __restrict__ Gh2, int N) {
  __shared__ float lM[64 * 256];             // 64 KB
  int t = threadIdx.x;
  const float4* Mf4 = (const float4*)Mf;
  float4* lM4 = (float4*)lM;
  for (int i = t; i < 4096; i += BD) lM4[i] = Mf4[i];
  __syncthreads();
  int lane = t & 63, w = t >> 6;
  int nloc0 = blockIdx.x * 64 + w * 16;
#pragma unroll
  for (int b = 0; b < 2; b++) {
    int nl = nloc0 + b * 8;
    float4 acc[8];
#pragma unroll
    for (int ni = 0; ni < 8; ni++) acc[ni] = make_float4(0.f, 0.f, 0.f, 0.f);
#pragma unroll 8
    for (int m = 0; m < 64; m++) {
      float4 Mv = lM4[m * 64 + lane];
#pragma unroll
      for (int ni = 0; ni < 8; ni++) {
        float em = emb[(size_t)(nl + ni) * 64 + m];   // over-read past N stays in ws
        acc[ni].x = fmaf(em, Mv.x, acc[ni].x);
        acc[ni].y = fmaf(em, Mv.y, acc[ni].y);
        acc[ni].z = fmaf(em, Mv.z, acc[ni].z);
        acc[ni].w = fmaf(em, Mv.w, acc[ni].w);
      }
    }
#pragma unroll
    for (int ni = 0; ni < 8; ni++)
      if (nl + ni < N) {
        __half2 h01 = __floats2half2_rn(acc[ni].x, acc[ni].y);
        __half2 h23 = __floats2half2_rn(acc[ni].z, acc[ni].w);
        uint2 st;
        st.x = *(unsigned int*)&h01;
        st.y = *(unsigned int*)&h23;
        Gh2[(size_t)(nl + ni) * 64 + lane] = st;
      }
  }
}

// ---------------- fused: att + softmax-den + S + S@Wv -> kg  (persistent, fp16-packed S) ----------------
__global__ __launch_bounds__(256) void k_fused(const float* __restrict__ emb,
                        const float* __restrict__ weight,
                        const uint4* __restrict__ Ghq, const float* __restrict__ Wv,
                        const int2* __restrict__ epack, const int* __restrict__ rowptr,
                        float* __restrict__ kg, int N) {
  __shared__ float SL[4 * 272];              // per-wave 4 segments of 68 (bank-skewed)
  int t = threadIdx.x, lane = t & 63, w = t >> 6, q = lane >> 4, s = lane & 15;
  float* L = SL + w * 272;
  int wid = blockIdx.x * 4 + w, nw = gridDim.x * 4;
  const __half2 z2 = __float2half2_rn(0.f);
  for (int n = wid; n < N; n += nw) {
    // G row (fp16 -> f32 regs)
    uint4 ga = Ghq[(size_t)n * 32 + s * 2];
    uint4 gb = Ghq[(size_t)n * 32 + s * 2 + 1];
    float2 ca = __half22float2(*(__half2*)&ga.x);
    float2 cb = __half22float2(*(__half2*)&ga.y);
    float4 G0 = make_float4(ca.x, ca.y, cb.x, cb.y);
    ca = __half22float2(*(__half2*)&ga.z);
    cb = __half22float2(*(__half2*)&ga.w);
    float4 G1 = make_float4(ca.x, ca.y, cb.x, cb.y);
    ca = __half22float2(*(__half2*)&gb.x);
    cb = __half22float2(*(__half2*)&gb.y);
    float4 G2 = make_float4(ca.x, ca.y, cb.x, cb.y);
    ca = __half22float2(*(__half2*)&gb.z);
    cb = __half22float2(*(__half2*)&gb.w);
    float4 G3 = make_float4(ca.x, ca.y, cb.x, cb.y);

    int base = rowptr[n], deg = rowptr[n + 1] - base;
    float4 den = make_float4(0.f, 0.f, 0.f, 0.f);
    // packed S accumulators: S<c>a = (head0,head1), S<c>b = (head2,head3)
    __half2 S0a = z2, S0b = z2, S1a = z2, S1b = z2;
    __half2 S2a = z2, S2b = z2, S3a = z2, S3b = z2;
    for (int g0 = 0; g0 < deg; g0 += 4) {
      int k = g0 + q;
      bool valid = (k < deg);
      int kk = min(k, deg - 1);
      int2 p = epack[base + kk];
      float4 e4 = *(const float4*)(emb + (size_t)p.x * 64 + s * 4);
      float4 r4 = *(const float4*)(weight + (size_t)p.y * 64 + s * 4);
      float4 x;
      x.x = e4.x * r4.x; x.y = e4.y * r4.y; x.z = e4.z * r4.z; x.w = e4.w * r4.w;
      float4 a;
      a.x = fmaf(x.x, G0.x, fmaf(x.y, G1.x, fmaf(x.z, G2.x, x.w * G3.x)));
      a.y = fmaf(x.x, G0.y, fmaf(x.y, G1.y, fmaf(x.z, G2.y, x.w * G3.y)));
      a.z = fmaf(x.x, G0.z, fmaf(x.y, G1.z, fmaf(x.z, G2.z, x.w * G3.z)));
      a.w = fmaf(x.x, G0.w, fmaf(x.y, G1.w, fmaf(x.z, G2.w, x.w * G3.w)));
      RED16(a.x) RED16(a.y) RED16(a.z) RED16(a.w)
      a.x = fminf(10.f, fmaxf(-10.f, a.x));
      a.y = fminf(10.f, fmaxf(-10.f, a.y));
      a.z = fminf(10.f, fmaxf(-10.f, a.z));
      a.w = fminf(10.f, fmaxf(-10.f, a.w));
      float4 ev;
      ev.x = valid ? __expf(a.x) : 0.f;
      ev.y = valid ? __expf(a.y) : 0.f;
      ev.z = valid ? __expf(a.z) : 0.f;
      ev.w = valid ? __expf(a.w) : 0.f;
      den.x += ev.x; den.y += ev.y; den.z += ev.z; den.w += ev.w;
      __half2 e01 = __floats2half2_rn(ev.x, ev.y);
      __half2 e23 = __floats2half2_rn(ev.z, ev.w);
      __half2 b;
      b = __float2half2_rn(x.x); S0a = __hfma2(e01, b, S0a); S0b = __hfma2(e23, b, S0b);
      b = __float2half2_rn(x.y); S1a = __hfma2(e01, b, S1a); S1b = __hfma2(e23, b, S1b);
      b = __float2half2_rn(x.z); S2a = __hfma2(e01, b, S2a); S2b = __hfma2(e23, b, S2b);
      b = __float2half2_rn(x.w); S3a = __hfma2(e01, b, S3a); S3b = __hfma2(e23, b, S3b);
    }
    REDQ(den.x) REDQ(den.y) REDQ(den.z) REDQ(den.w)
    REDQH(S0a) REDQH(S0b) REDQH(S1a) REDQH(S1b)
    REDQH(S2a) REDQH(S2b) REDQH(S3a) REDQH(S3b)
    float4 inv;
    inv.x = 1.f / (den.x + 1e-8f); inv.y = 1.f / (den.y + 1e-8f);
    inv.z = 1.f / (den.z + 1e-8f); inv.w = 1.f / (den.w + 1e-8f);
    // convert + normalize: s<c>h<h> = S[comp c][head h] / den[h]
    float2 c0, c1;
    c0 = __half22float2(S0a); c1 = __half22float2(S0b);
    float s0h0 = c0.x * inv.x, s0h1 = c0.y * inv.y, s0h2 = c1.x * inv.z, s0h3 = c1.y * inv.w;
    c0 = __half22float2(S1a); c1 = __half22float2(S1b);
    float s1h0 = c0.x * inv.x, s1h1 = c0.y * inv.y, s1h2 = c1.x * inv.z, s1h3 = c1.y * inv.w;
    c0 = __half22float2(S2a); c1 = __half22float2(S2b);
    float s2h0 = c0.x * inv.x, s2h1 = c0.y * inv.y, s2h2 = c1.x * inv.z, s2h3 = c1.y * inv.w;
    c0 = __half22float2(S3a); c1 = __half22float2(S3b);
    float s3h0 = c0.x * inv.x, s3h1 = c0.y * inv.y, s3h2 = c1.x * inv.z, s3h3 = c1.y * inv.w;
    if (q == 0) {
      *(float4*)(L +       s * 4) = make_float4(s0h0, s1h0, s2h0, s3h0);
      *(float4*)(L +  68 + s * 4) = make_float4(s0h1, s1h1, s2h1, s3h1);
      *(float4*)(L + 136 + s * 4) = make_float4(s0h2, s1h2, s2h2, s3h2);
      *(float4*)(L + 204 + s * 4) = make_float4(s0h3, s1h3, s2h3, s3h3);
    }
    const float4* L4 = (const float4*)(L + q * 68);
    float acc = 0.f;
#pragma unroll
    for (int i4 = 0; i4 < 16; i4++) {
      float4 Lv = L4[i4];
      acc = fmaf(Lv.x, Wv[(i4 * 4 + 0) * 64 + lane], acc);
      acc = fmaf(Lv.y, Wv[(i4 * 4 + 1) * 64 + lane], acc);
      acc = fmaf(Lv.z, Wv[(i4 * 4 + 2) * 64 + lane], acc);
      acc = fmaf(Lv.w, Wv[(i4 * 4 + 3) * 64 + lane], acc);
    }
    kg[(size_t)n * 64 + lane] = acc;
  }
}

// ---------------- D = KG^2 @ REL^2T  (64 nodes/block, LDS-staged) ----------------
__global__ __launch_bounds__(256) void k_d(const float4* __restrict__ kg4,
                    const float* __restrict__ weight,
                    float* __restrict__ D, int N) {
  __shared__ float R2T[64 * 32];       // [j][r] = weight[r][j]^2
  __shared__ float KG2[64 * 68];       // [node][j] padded
  int t = threadIdx.x;
  for (int i = t; i < 2048; i += BD) {
    int j = i >> 5, r = i & 31;
    float v = (r < 31) ? weight[r * 64 + j] : 0.f;
    R2T[i] = v * v;
  }
  int nbase = blockIdx.x * 64;
  const float4* src = kg4 + (size_t)nbase * 16;
#pragma unroll
  for (int i = 0; i < 4; i++) {
    int idx = t + i * 256;
    float4 v = src[idx];               // may over-read past N into adjacent ws: safe
    float* dst = KG2 + (idx >> 4) * 68 + (idx & 15) * 4;
    dst[0] = v.x * v.x; dst[1] = v.y * v.y; dst[2] = v.z * v.z; dst[3] = v.w * v.w;
  }
  __syncthreads();
  int r = t & 31, ng = t >> 5;
  float acc[8] = {0.f, 0.f, 0.f, 0.f, 0.f, 0.f, 0.f, 0.f};
  const float* kbase = KG2 + ng * 8 * 68;
#pragma unroll 4
  for (int j4 = 0; j4 < 16; j4++) {
    float r0 = R2T[(j4 * 4 + 0) * 32 + r];
    float r1 = R2T[(j4 * 4 + 1) * 32 + r];
    float r2 = R2T[(j4 * 4 + 2) * 32 + r];
    float r3 = R2T[(j4 * 4 + 3) * 32 + r];
#pragma unroll
    for (int ni = 0; ni < 8; ni++) {
      float4 kv = *(const float4*)(kbase + ni * 68 + j4 * 4);
      acc[ni] = fmaf(kv.w, r3, fmaf(kv.z, r2, fmaf(kv.y, r1, fmaf(kv.x, r0, acc[ni]))));
    }
  }
  if (r < 31) {
    int nlim = N - nbase;
#pragma unroll
    for (int ni = 0; ni < 8; ni++) {
      int nl = ng * 8 + ni;
      if (nl < nlim) D[(size_t)(nbase + nl) * 32 + r] = acc[ni];
    }
  }
}

// ---------------- scatter-softmax + aggregation + normalize + residual (persistent) ----------------
__global__ __launch_bounds__(256) void k_aggnorm(const float* __restrict__ emb,
                          const float* __restrict__ D,
                          const int2* __restrict__ epack, const int* __restrict__ rowptr,
                          float* __restrict__ embn, float* __restrict__ out, int N) {
  __shared__ float wls[4 * CAP];
  __shared__ float DnL[4 * 32];
  int t = threadIdx.x, lane = t & 63, w = t >> 6, q = lane >> 4, s = lane & 15;
  float* wl = wls + w * CAP;
  float* Dn = DnL + w * 32;
  int wid = blockIdx.x * 4 + w, nw = gridDim.x * 4;
  for (int n = wid; n < N; n += nw) {
    int base = rowptr[n], deg = rowptr[n + 1] - base;
    if (lane < 32) Dn[lane] = (lane < 31) ? D[(size_t)n * 32 + lane] : 0.f;
    float4 agg = make_float4(0.f, 0.f, 0.f, 0.f);
    float sacc = 0.f;
    float m = -1e30f;
    if (deg > 0) {
      for (int k = lane; k < deg; k += 64) {
        int2 p = epack[base + k];
        float wv = Dn[p.y] * D[(size_t)p.x * 32 + p.y];
        if (k < CAP) wl[k] = wv;
        m = fmaxf(m, wv);
      }
#pragma unroll
      for (int off = 32; off >= 1; off >>= 1) m = fmaxf(m, __shfl_xor(m, off, 64));
      for (int g0 = 0; g0 < deg; g0 += 4) {
        int k = g0 + q;
        bool valid = (k < deg);
        int kk = min(k, deg - 1);
        int2 p = epack[base + kk];
        float4 e4 = *(const float4*)(emb + (size_t)p.x * 64 + s * 4);
        float wv = (kk < CAP) ? wl[kk] : Dn[p.y] * D[(size_t)p.x * 32 + p.y];
        float a = valid ? __expf(wv - m) : 0.f;
        sacc += a;
        agg.x = fmaf(a, e4.x, agg.x);
        agg.y = fmaf(a, e4.y, agg.y);
        agg.z = fmaf(a, e4.z, agg.z);
        agg.w = fmaf(a, e4.w, agg.w);
      }
    }
    REDQ(sacc)
    REDQ(agg.x) REDQ(agg.y) REDQ(agg.z) REDQ(agg.w)
    float sinv = 1.f / (sacc + 1e-16f);
    agg.x *= sinv; agg.y *= sinv; agg.z *= sinv; agg.w *= sinv;
    float ss = agg.x * agg.x + agg.y * agg.y + agg.z * agg.z + agg.w * agg.w;
    RED16(ss)
    float nr = fmaxf(sqrtf(ss), 1e-12f);
    float rin = 1.f / nr;
    float4 en;
    en.x = agg.x * rin; en.y = agg.y * rin; en.z = agg.z * rin; en.w = agg.w * rin;
    if (q == 0) {
      float4* eo = (float4*)(embn + (size_t)n * 64) + s;
      *eo = en;
      float4* oo = (float4*)(out + (size_t)n * 64) + s;
      float4 ov = *oo;
      ov.x += en.x; ov.y += en.y; ov.z += en.z; ov.w += en.w;
      *oo = ov;
    }
  }
}

extern "C" void kernel_launch(void* const* d_in, const int* in_sizes, int n_in,
                              void* d_out, int out_size, void* d_ws, size_t ws_size,
                              hipStream_t stream) {
  const float* ent    = (const float*)d_in[0];
  const float* weight = (const float*)d_in[1];
  const float* Wq     = (const float*)d_in[2];
  const float* Wk     = (const float*)d_in[3];
  const float* Wv     = (const float*)d_in[4];
  const int*   eidx   = (const int*)d_in[5];
  const int*   etype  = (const int*)d_in[6];
  int N = in_sizes[0] / 64;
  int E = in_sizes[6];
  const int* head = eidx;
  const int* tail = eidx + E;

  // workspace layout (float units)
  float* ws   = (float*)d_ws;
  size_t o = 0;
  float* embA = ws + o; o += (size_t)N * 64;
  float* embB = ws + o; o += (size_t)N * 64;
  float* Gbuf = ws + o; o += (size_t)N * 128;    // fp16 G (N*256 halves); reused as D (N*32 f32)
  float* Mf   = ws + o; o += 64 * 256;
  int2* epack = (int2*)(ws + o); o += (size_t)E * 2;
  int* rowptr = (int*)(ws + o); o += N + 1;
  int* deg    = (int*)(ws + o); o += N;
  int* cur    = (int*)(ws + o); o += N;
  int* bsum   = (int*)(ws + o); o += 512;
  int* boff   = (int*)(ws + o); o += 512;
  float* Dbuf = Gbuf;

  int n4  = N * 64 / 4;
  int bl4 = (n4 + BD - 1) / BD;
  int ebl = (E + BD - 1) / BD;
  int sbl = (N + BD - 1) / BD;

  k_init<<<bl4, BD, 0, stream>>>((const float4*)ent, (float4*)embA, (float4*)d_out,
                                 n4, deg, N);
  k_deg    <<<ebl, BD, 0, stream>>>(head, deg, E);
  k_scan_a <<<sbl, BD, 0, stream>>>(deg, rowptr, bsum, N);
  k_scan_b <<<1, 512, 0, stream>>>(bsum, boff, sbl);
  k_scan_c <<<sbl, BD, 0, stream>>>(rowptr, cur, boff, N, E);
  k_scatter<<<ebl, BD, 0, stream>>>(head, tail, etype, cur, epack, E);

  float* emb = embA;
  float* alt = embB;
  for (int l = 0; l < 2; l++) {
    const float* wq = Wq + (size_t)l * 64 * 64;
    const float* wk = Wk + (size_t)l * 64 * 64;
    const float* wv = Wv + (size_t)l * 64 * 64;

    k_m<<<64, BD, 0, stream>>>(wq, wk, Mf);
    k_g<<<(N + 63) / 64, BD, 0, stream>>>(emb, Mf, (uint2*)Gbuf, N);
    k_fused<<<PBLK, BD, 0, stream>>>(emb, weight, (const uint4*)Gbuf,
                                     wv, epack, rowptr, alt, N);
    k_d<<<(N + 63) / 64, BD, 0, stream>>>((const float4*)alt, weight, Dbuf, N);
    k_aggnorm<<<PBLK, BD, 0, stream>>>(emb, Dbuf, epack, rowptr,
                                       alt, (float*)d_out, N);
    float* tmp = emb; emb = alt; alt = tmp;
  }
}

// Round 13
// 615.760 us; speedup vs baseline: 1.1855x; 1.0395x over previous
//
#include <hip/hip_runtime.h>
#include <hip/hip_fp16.h>
#include <math.h>

#define BD 256
#define CAP 192
#define PBLK 2048

#define RED16(v) { v += __shfl_xor(v, 1, 64); v += __shfl_xor(v, 2, 64); \
                   v += __shfl_xor(v, 4, 64); v += __shfl_xor(v, 8, 64); }
#define REDQ(v)  { v += __shfl_xor(v, 16, 64); v += __shfl_xor(v, 32, 64); }

__device__ __forceinline__ __half2 shflxor_h2(__half2 v, int off) {
  int i = __shfl_xor(*(int*)&v, off, 64);
  return *(__half2*)&i;
}
#define REDQH(v)  { v = __hadd2(v, shflxor_h2(v, 16)); v = __hadd2(v, shflxor_h2(v, 32)); }
#define RED16H(v) { v = __hadd2(v, shflxor_h2(v, 1)); v = __hadd2(v, shflxor_h2(v, 2)); \
                    v = __hadd2(v, shflxor_h2(v, 4)); v = __hadd2(v, shflxor_h2(v, 8)); }

// ---------------- init: res = emb_cur = entity_emb; deg = 0 ----------------
__global__ void k_init(const float4* __restrict__ ent, float4* __restrict__ emb,
                       float4* __restrict__ out, int n4, int* __restrict__ deg, int N) {
  int i = blockIdx.x * BD + threadIdx.x;
  if (i < n4) { float4 v = ent[i]; emb[i] = v; out[i] = v; }
  if (i < N) deg[i] = 0;
}

// ---------------- CSR build ----------------
__global__ void k_deg(const int* __restrict__ head, int* __restrict__ deg, int E) {
  int e = blockIdx.x * BD + threadIdx.x;
  if (e < E) atomicAdd(&deg[head[e]], 1);
}

__global__ void k_scan_a(const int* __restrict__ deg, int* __restrict__ rowptr,
                         int* __restrict__ bsum, int N) {
  __shared__ int s[BD];
  int t = threadIdx.x, i = blockIdx.x * BD + t;
  int v = (i < N) ? deg[i] : 0;
  s[t] = v; __syncthreads();
  for (int off = 1; off < BD; off <<= 1) {
    int add = (t >= off) ? s[t - off] : 0;
    __syncthreads();
    s[t] += add;
    __syncthreads();
  }
  if (i < N) rowptr[i] = s[t] - v;
  if (t == BD - 1) bsum[blockIdx.x] = s[t];
}

__global__ void k_scan_b(const int* __restrict__ bsum, int* __restrict__ boff, int nb) {
  __shared__ int s[512];
  int t = threadIdx.x;
  int v = (t < nb) ? bsum[t] : 0;
  s[t] = v; __syncthreads();
  for (int off = 1; off < 512; off <<= 1) {
    int add = (t >= off) ? s[t - off] : 0;
    __syncthreads();
    s[t] += add;
    __syncthreads();
  }
  boff[t] = s[t] - v;
}

__global__ void k_scan_c(int* __restrict__ rowptr, int* __restrict__ cur,
                         const int* __restrict__ boff, int N, int E) {
  int i = blockIdx.x * BD + threadIdx.x;
  if (i < N) { int v = rowptr[i] + boff[blockIdx.x]; rowptr[i] = v; cur[i] = v; }
  if (i == 0) rowptr[N] = E;
}

__global__ void k_scatter(const int* __restrict__ head, const int* __restrict__ tail,
                          const int* __restrict__ etype,
                          int* __restrict__ cur, int2* __restrict__ epack, int E) {
  int e = blockIdx.x * BD + threadIdx.x;
  if (e < E) {
    int p = atomicAdd(&cur[head[e]], 1);
    epack[p] = make_int2(tail[e], etype[e] - 1);
  }
}

// ---------------- M_h = Wq_h @ Wk_h^T : Mf[m][i*4+h] ----------------
__global__ void k_m(const float* __restrict__ Wq, const float* __restrict__ Wk,
                    float* __restrict__ Mf) {
  int tid = blockIdx.x * BD + threadIdx.x;   // 0..16383
  int c = tid & 255;
  int m = tid >> 8;
  int i = c >> 2, h = c & 3;
  const float* wq = Wq + m * 64 + h * 16;
  const float* wk = Wk + i * 64 + h * 16;
  float acc = 0.f;
#pragma unroll
  for (int d = 0; d < 16; d++) acc = fmaf(wq[d], wk[d], acc);
  Mf[tid] = acc;
}

// ---------------- G = emb @ Mf  -> fp16  (LDS-tiled, 64 nodes/block) ----------------
__global__ __launch_bounds__(256) void k_g(const float* __restrict__ emb,
                                           const float* __restrict__ Mf,
                                           uint2* __restrict__ Gh2, int N) {
  __shared__ float lM[64 * 256];             // 64 KB
  int t = threadIdx.x;
  const float4* Mf4 = (const float4*)Mf;
  float4* lM4 = (float4*)lM;
  for (int i = t; i < 4096; i += BD) lM4[i] = Mf4[i];
  __syncthreads();
  int lane = t & 63, w = t >> 6;
  int nloc0 = blockIdx.x * 64 + w * 16;
#pragma unroll
  for (int b = 0; b < 2; b++) {
    int nl = nloc0 + b * 8;
    float4 acc[8];
#pragma unroll
    for (int ni = 0; ni < 8; ni++) acc[ni] = make_float4(0.f, 0.f, 0.f, 0.f);
#pragma unroll 8
    for (int m = 0; m < 64; m++) {
      float4 Mv = lM4[m * 64 + lane];
#pragma unroll
      for (int ni = 0; ni < 8; ni++) {
        float em = emb[(size_t)(nl + ni) * 64 + m];   // over-read past N stays in ws
        acc[ni].x = fmaf(em, Mv.x, acc[ni].x);
        acc[ni].y = fmaf(em, Mv.y, acc[ni].y);
        acc[ni].z = fmaf(em, Mv.z, acc[ni].z);
        acc[ni].w = fmaf(em, Mv.w, acc[ni].w);
      }
    }
#pragma unroll
    for (int ni = 0; ni < 8; ni++)
      if (nl + ni < N) {
        __half2 h01 = __floats2half2_rn(acc[ni].x, acc[ni].y);
        __half2 h23 = __floats2half2_rn(acc[ni].z, acc[ni].w);
        uint2 st;
        st.x = *(unsigned int*)&h01;
        st.y = *(unsigned int*)&h23;
        Gh2[(size_t)(nl + ni) * 64 + lane] = st;
      }
  }
}

// ---------------- fused: att + softmax-den + S + S@Wv -> kg (persistent, fully-packed fp16) ----------------
__global__ __launch_bounds__(256) void k_fused(const float* __restrict__ emb,
                        const float* __restrict__ weight,
                        const uint4* __restrict__ Ghq, const float* __restrict__ Wv,
                        const int2* __restrict__ epack, const int* __restrict__ rowptr,
                        float* __restrict__ kg, int N) {
  __shared__ float SL[4 * 272];              // per-wave 4 segments of 68 (bank-skewed)
  int t = threadIdx.x, lane = t & 63, w = t >> 6, q = lane >> 4, s = lane & 15;
  float* L = SL + w * 272;
  int wid = blockIdx.x * 4 + w, nw = gridDim.x * 4;
  const __half2 z2 = __float2half2_rn(0.f);
  for (int n = wid; n < N; n += nw) {
    // G row stays PACKED: 8 half2 regs. ga = comps 4s,4s+1; gb = comps 4s+2,4s+3 (h01,h23 each)
    uint4 ga = Ghq[(size_t)n * 32 + s * 2];
    uint4 gb = Ghq[(size_t)n * 32 + s * 2 + 1];
    __half2 c0h01 = *(__half2*)&ga.x, c0h23 = *(__half2*)&ga.y;
    __half2 c1h01 = *(__half2*)&ga.z, c1h23 = *(__half2*)&ga.w;
    __half2 c2h01 = *(__half2*)&gb.x, c2h23 = *(__half2*)&gb.y;
    __half2 c3h01 = *(__half2*)&gb.z, c3h23 = *(__half2*)&gb.w;

    int base = rowptr[n], deg = rowptr[n + 1] - base;
    float4 den = make_float4(0.f, 0.f, 0.f, 0.f);
    __half2 S0a = z2, S0b = z2, S1a = z2, S1b = z2;
    __half2 S2a = z2, S2b = z2, S3a = z2, S3b = z2;
    for (int g0 = 0; g0 < deg; g0 += 4) {
      int k = g0 + q;
      bool valid = (k < deg);
      int kk = min(k, deg - 1);
      int2 p = epack[base + kk];
      float4 e4 = *(const float4*)(emb + (size_t)p.x * 64 + s * 4);
      float4 r4 = *(const float4*)(weight + (size_t)p.y * 64 + s * 4);
      __half2 x01 = __floats2half2_rn(e4.x * r4.x, e4.y * r4.y);
      __half2 x23 = __floats2half2_rn(e4.z * r4.z, e4.w * r4.w);
      __half2 b0 = __low2half2(x01), b1 = __high2half2(x01);
      __half2 b2 = __low2half2(x23), b3 = __high2half2(x23);
      // attention partials, packed per head-pair
      __half2 a01 = __hmul2(b0, c0h01);
      a01 = __hfma2(b1, c1h01, a01);
      a01 = __hfma2(b2, c2h01, a01);
      a01 = __hfma2(b3, c3h01, a01);
      __half2 a23 = __hmul2(b0, c0h23);
      a23 = __hfma2(b1, c1h23, a23);
      a23 = __hfma2(b2, c2h23, a23);
      a23 = __hfma2(b3, c3h23, a23);
      RED16H(a01) RED16H(a23)
      float2 fa01 = __half22float2(a01);
      float2 fa23 = __half22float2(a23);
      fa01.x = fminf(10.f, fmaxf(-10.f, fa01.x));
      fa01.y = fminf(10.f, fmaxf(-10.f, fa01.y));
      fa23.x = fminf(10.f, fmaxf(-10.f, fa23.x));
      fa23.y = fminf(10.f, fmaxf(-10.f, fa23.y));
      float4 ev;
      ev.x = valid ? __expf(fa01.x) : 0.f;
      ev.y = valid ? __expf(fa01.y) : 0.f;
      ev.z = valid ? __expf(fa23.x) : 0.f;
      ev.w = valid ? __expf(fa23.y) : 0.f;
      den.x += ev.x; den.y += ev.y; den.z += ev.z; den.w += ev.w;
      __half2 e01 = __floats2half2_rn(ev.x, ev.y);
      __half2 e23 = __floats2half2_rn(ev.z, ev.w);
      S0a = __hfma2(e01, b0, S0a); S0b = __hfma2(e23, b0, S0b);
      S1a = __hfma2(e01, b1, S1a); S1b = __hfma2(e23, b1, S1b);
      S2a = __hfma2(e01, b2, S2a); S2b = __hfma2(e23, b2, S2b);
      S3a = __hfma2(e01, b3, S3a); S3b = __hfma2(e23, b3, S3b);
    }
    REDQ(den.x) REDQ(den.y) REDQ(den.z) REDQ(den.w)
    REDQH(S0a) REDQH(S0b) REDQH(S1a) REDQH(S1b)
    REDQH(S2a) REDQH(S2b) REDQH(S3a) REDQH(S3b)
    float4 inv;
    inv.x = 1.f / (den.x + 1e-8f); inv.y = 1.f / (den.y + 1e-8f);
    inv.z = 1.f / (den.z + 1e-8f); inv.w = 1.f / (den.w + 1e-8f);
    float2 c0, c1;
    c0 = __half22float2(S0a); c1 = __half22float2(S0b);
    float s0h0 = c0.x * inv.x, s0h1 = c0.y * inv.y, s0h2 = c1.x * inv.z, s0h3 = c1.y * inv.w;
    c0 = __half22float2(S1a); c1 = __half22float2(S1b);
    float s1h0 = c0.x * inv.x, s1h1 = c0.y * inv.y, s1h2 = c1.x * inv.z, s1h3 = c1.y * inv.w;
    c0 = __half22float2(S2a); c1 = __half22float2(S2b);
    float s2h0 = c0.x * inv.x, s2h1 = c0.y * inv.y, s2h2 = c1.x * inv.z, s2h3 = c1.y * inv.w;
    c0 = __half22float2(S3a); c1 = __half22float2(S3b);
    float s3h0 = c0.x * inv.x, s3h1 = c0.y * inv.y, s3h2 = c1.x * inv.z, s3h3 = c1.y * inv.w;
    if (q == 0) {
      *(float4*)(L +       s * 4) = make_float4(s0h0, s1h0, s2h0, s3h0);
      *(float4*)(L +  68 + s * 4) = make_float4(s0h1, s1h1, s2h1, s3h1);
      *(float4*)(L + 136 + s * 4) = make_float4(s0h2, s1h2, s2h2, s3h2);
      *(float4*)(L + 204 + s * 4) = make_float4(s0h3, s1h3, s2h3, s3h3);
    }
    const float4* L4 = (const float4*)(L + q * 68);
    float acc = 0.f;
#pragma unroll
    for (int i4 = 0; i4 < 16; i4++) {
      float4 Lv = L4[i4];
      acc = fmaf(Lv.x, Wv[(i4 * 4 + 0) * 64 + lane], acc);
      acc = fmaf(Lv.y, Wv[(i4 * 4 + 1) * 64 + lane], acc);
      acc = fmaf(Lv.z, Wv[(i4 * 4 + 2) * 64 + lane], acc);
      acc = fmaf(Lv.w, Wv[(i4 * 4 + 3) * 64 + lane], acc);
    }
    kg[(size_t)n * 64 + lane] = acc;
  }
}

// ---------------- D = KG^2 @ REL^2T  (64 nodes/block, LDS-staged) ----------------
__global__ __launch_bounds__(256) void k_d(const float4* __restrict__ kg4,
                    const float* __restrict__ weight,
                    float* __restrict__ D, int N) {
  __shared__ float R2T[64 * 32];       // [j][r] = weight[r][j]^2
  __shared__ float KG2[64 * 68];       // [node][j] padded
  int t = threadIdx.x;
  for (int i = t; i < 2048; i += BD) {
    int j = i >> 5, r = i & 31;
    float v = (r < 31) ? weight[r * 64 + j] : 0.f;
    R2T[i] = v * v;
  }
  int nbase = blockIdx.x * 64;
  const float4* src = kg4 + (size_t)nbase * 16;
#pragma unroll
  for (int i = 0; i < 4; i++) {
    int idx = t + i * 256;
    float4 v = src[idx];               // may over-read past N into adjacent ws: safe
    float* dst = KG2 + (idx >> 4) * 68 + (idx & 15) * 4;
    dst[0] = v.x * v.x; dst[1] = v.y * v.y; dst[2] = v.z * v.z; dst[3] = v.w * v.w;
  }
  __syncthreads();
  int r = t & 31, ng = t >> 5;
  float acc[8] = {0.f, 0.f, 0.f, 0.f, 0.f, 0.f, 0.f, 0.f};
  const float* kbase = KG2 + ng * 8 * 68;
#pragma unroll 4
  for (int j4 = 0; j4 < 16; j4++) {
    float r0 = R2T[(j4 * 4 + 0) * 32 + r];
    float r1 = R2T[(j4 * 4 + 1) * 32 + r];
    float r2 = R2T[(j4 * 4 + 2) * 32 + r];
    float r3 = R2T[(j4 * 4 + 3) * 32 + r];
#pragma unroll
    for (int ni = 0; ni < 8; ni++) {
      float4 kv = *(const float4*)(kbase + ni * 68 + j4 * 4);
      acc[ni] = fmaf(kv.w, r3, fmaf(kv.z, r2, fmaf(kv.y, r1, fmaf(kv.x, r0, acc[ni]))));
    }
  }
  if (r < 31) {
    int nlim = N - nbase;
#pragma unroll
    for (int ni = 0; ni < 8; ni++) {
      int nl = ng * 8 + ni;
      if (nl < nlim) D[(size_t)(nbase + nl) * 32 + r] = acc[ni];
    }
  }
}

// ---------------- scatter-softmax + aggregation + normalize + residual (persistent) ----------------
__global__ __launch_bounds__(256) void k_aggnorm(const float* __restrict__ emb,
                          const float* __restrict__ D,
                          const int2* __restrict__ epack, const int* __restrict__ rowptr,
                          float* __restrict__ embn, float* __restrict__ out, int N) {
  __shared__ float wls[4 * CAP];
  __shared__ float DnL[4 * 32];
  int t = threadIdx.x, lane = t & 63, w = t >> 6, q = lane >> 4, s = lane & 15;
  float* wl = wls + w * CAP;
  float* Dn = DnL + w * 32;
  int wid = blockIdx.x * 4 + w, nw = gridDim.x * 4;
  for (int n = wid; n < N; n += nw) {
    int base = rowptr[n], deg = rowptr[n + 1] - base;
    if (lane < 32) Dn[lane] = (lane < 31) ? D[(size_t)n * 32 + lane] : 0.f;
    float4 agg = make_float4(0.f, 0.f, 0.f, 0.f);
    float sacc = 0.f;
    float m = -1e30f;
    if (deg > 0) {
      for (int k = lane; k < deg; k += 64) {
        int2 p = epack[base + k];
        float wv = Dn[p.y] * D[(size_t)p.x * 32 + p.y];
        if (k < CAP) wl[k] = wv;
        m = fmaxf(m, wv);
      }
#pragma unroll
      for (int off = 32; off >= 1; off >>= 1) m = fmaxf(m, __shfl_xor(m, off, 64));
      for (int g0 = 0; g0 < deg; g0 += 4) {
        int k = g0 + q;
        bool valid = (k < deg);
        int kk = min(k, deg - 1);
        int2 p = epack[base + kk];
        float4 e4 = *(const float4*)(emb + (size_t)p.x * 64 + s * 4);
        float wv = (kk < CAP) ? wl[kk] : Dn[p.y] * D[(size_t)p.x * 32 + p.y];
        float a = valid ? __expf(wv - m) : 0.f;
        sacc += a;
        agg.x = fmaf(a, e4.x, agg.x);
        agg.y = fmaf(a, e4.y, agg.y);
        agg.z = fmaf(a, e4.z, agg.z);
        agg.w = fmaf(a, e4.w, agg.w);
      }
    }
    REDQ(sacc)
    REDQ(agg.x) REDQ(agg.y) REDQ(agg.z) REDQ(agg.w)
    float sinv = 1.f / (sacc + 1e-16f);
    agg.x *= sinv; agg.y *= sinv; agg.z *= sinv; agg.w *= sinv;
    float ss = agg.x * agg.x + agg.y * agg.y + agg.z * agg.z + agg.w * agg.w;
    RED16(ss)
    float nr = fmaxf(sqrtf(ss), 1e-12f);
    float rin = 1.f / nr;
    float4 en;
    en.x = agg.x * rin; en.y = agg.y * rin; en.z = agg.z * rin; en.w = agg.w * rin;
    if (q == 0) {
      float4* eo = (float4*)(embn + (size_t)n * 64) + s;
      *eo = en;
      float4* oo = (float4*)(out + (size_t)n * 64) + s;
      float4 ov = *oo;
      ov.x += en.x; ov.y += en.y; ov.z += en.z; ov.w += en.w;
      *oo = ov;
    }
  }
}

extern "C" void kernel_launch(void* const* d_in, const int* in_sizes, int n_in,
                              void* d_out, int out_size, void* d_ws, size_t ws_size,
                              hipStream_t stream) {
  const float* ent    = (const float*)d_in[0];
  const float* weight = (const float*)d_in[1];
  const float* Wq     = (const float*)d_in[2];
  const float* Wk     = (const float*)d_in[3];
  const float* Wv     = (const float*)d_in[4];
  const int*   eidx   = (const int*)d_in[5];
  const int*   etype  = (const int*)d_in[6];
  int N = in_sizes[0] / 64;
  int E = in_sizes[6];
  const int* head = eidx;
  const int* tail = eidx + E;

  // workspace layout (float units)
  float* ws   = (float*)d_ws;
  size_t o = 0;
  float* embA = ws + o; o += (size_t)N * 64;
  float* embB = ws + o; o += (size_t)N * 64;
  float* Gbuf = ws + o; o += (size_t)N * 128;    // fp16 G (N*256 halves); reused as D (N*32 f32)
  float* Mf   = ws + o; o += 64 * 256;
  int2* epack = (int2*)(ws + o); o += (size_t)E * 2;
  int* rowptr = (int*)(ws + o); o += N + 1;
  int* deg    = (int*)(ws + o); o += N;
  int* cur    = (int*)(ws + o); o += N;
  int* bsum   = (int*)(ws + o); o += 512;
  int* boff   = (int*)(ws + o); o += 512;
  float* Dbuf = Gbuf;

  int n4  = N * 64 / 4;
  int bl4 = (n4 + BD - 1) / BD;
  int ebl = (E + BD - 1) / BD;
  int sbl = (N + BD - 1) / BD;

  k_init<<<bl4, BD, 0, stream>>>((const float4*)ent, (float4*)embA, (float4*)d_out,
                                 n4, deg, N);
  k_deg    <<<ebl, BD, 0, stream>>>(head, deg, E);
  k_scan_a <<<sbl, BD, 0, stream>>>(deg, rowptr, bsum, N);
  k_scan_b <<<1, 512, 0, stream>>>(bsum, boff, sbl);
  k_scan_c <<<sbl, BD, 0, stream>>>(rowptr, cur, boff, N, E);
  k_scatter<<<ebl, BD, 0, stream>>>(head, tail, etype, cur, epack, E);

  float* emb = embA;
  float* alt = embB;
  for (int l = 0; l < 2; l++) {
    const float* wq = Wq + (size_t)l * 64 * 64;
    const float* wk = Wk + (size_t)l * 64 * 64;
    const float* wv = Wv + (size_t)l * 64 * 64;

    k_m<<<64, BD, 0, stream>>>(wq, wk, Mf);
    k_g<<<(N + 63) / 64, BD, 0, stream>>>(emb, Mf, (uint2*)Gbuf, N);
    k_fused<<<PBLK, BD, 0, stream>>>(emb, weight, (const uint4*)Gbuf,
                                     wv, epack, rowptr, alt, N);
    k_d<<<(N + 63) / 64, BD, 0, stream>>>((const float4*)alt, weight, Dbuf, N);
    k_aggnorm<<<PBLK, BD, 0, stream>>>(emb, Dbuf, epack, rowptr,
                                       alt, (float*)d_out, N);
    float* tmp = emb; emb = alt; alt = tmp;
  }
}